// Round 17
// baseline (217.596 us; speedup 1.0000x reference)
//
#include <hip/hip_runtime.h>
#include <hip/hip_bf16.h>

// GraphConv: out[t] = sum_{e: tidx[e]==t} input[sidx[e]] * (esgn[e]*enorm[e])
// N_NODES=100000, N_FEAT=128, N_EDGES=600000, fp32.
//
// Round 17 = round 16 (67.7us) + overhead cuts:
//  - Gather prefix: per-wave shfl scans + wave-total combine (2 barriers,
//    was 16 Hillis-Steele barrier rounds).
//  - fixup_ovf folded into the LAST gather block (done-counter +
//    __threadfence) -> one dispatch fewer. ovf is ~empty (deg>24 only).

#define NCHUNK 256
#define BSHIFT 6
#define BNODES 64
#define NCAP   24
#define MAXB   2048

typedef float f32x2 __attribute__((ext_vector_type(2)));
typedef float f32x4 __attribute__((ext_vector_type(4)));

struct Ovf { int t; int src; float w; };

__device__ __forceinline__ unsigned bf16rne(float f) {
    unsigned u = __builtin_bit_cast(unsigned, f);
    return (u + 0x7FFFu + ((u >> 16) & 1u)) >> 16;
}

__device__ __forceinline__ void push_ovf(Ovf* ovf, int* ovf_count, int ovf_cap,
                                         int t, int s, float w) {
    const int o = atomicAdd(ovf_count, 1);
    if (o < ovf_cap) { Ovf v; v.t = t; v.src = s; v.w = w; ovf[o] = v; }
}

// A: blocks [0,NCHUNK): per-chunk hist -> scan -> place (exact CSR, dense
//    8B record writes). blocks [NCHUNK,..): fp32 -> bf16 shadow convert.
__global__ __launch_bounds__(256)
void build_convert(const int* __restrict__ tidx,
                   const int* __restrict__ sidx,
                   const float* __restrict__ enorm,
                   const float* __restrict__ esgn,
                   int* __restrict__ subcnt,     // [nb][NCHUNK]
                   int* __restrict__ suboff,     // [nb][NCHUNK]
                   unsigned long long* __restrict__ records,
                   int* __restrict__ ovf_count,  // [0]=ovf count, [1]=done count
                   int n_edges, int nbuckets, int epc,
                   const float* __restrict__ input,
                   unsigned* __restrict__ input_bf,
                   int n_cvt8) {
    if ((int)blockIdx.x < NCHUNK) {
        __shared__ int s_cnt[MAXB];
        __shared__ int s_off[MAXB];
        __shared__ int s_part[256];
        const int chunk = blockIdx.x;
        const int tid   = threadIdx.x;

        if (chunk == 0 && tid < 2) ovf_count[tid] = 0;   // ovf + done counters

        for (int i = tid; i < nbuckets; i += 256) s_cnt[i] = 0;
        __syncthreads();

        const int e0 = chunk * epc;
        const int e1 = min(e0 + epc, n_edges);
        for (int e = e0 + tid; e < e1; e += 256)
            atomicAdd(&s_cnt[tidx[e] >> BSHIFT], 1);
        __syncthreads();

        // Exclusive scan over nbuckets (<=MAXB): 8/thread + partials scan.
        int local[8];
        int sum = 0;
        #pragma unroll
        for (int k = 0; k < 8; ++k) {
            const int idx = tid * 8 + k;
            local[k] = (idx < nbuckets) ? s_cnt[idx] : 0;
            sum += local[k];
        }
        s_part[tid] = sum;
        __syncthreads();
        for (int d = 1; d < 256; d <<= 1) {
            const int v = (tid >= d) ? s_part[tid - d] : 0;
            __syncthreads();
            s_part[tid] += v;
            __syncthreads();
        }
        int run = s_part[tid] - sum;
        #pragma unroll
        for (int k = 0; k < 8; ++k) {
            const int idx = tid * 8 + k;
            if (idx < nbuckets) { s_off[idx] = run; run += local[k]; }
        }
        __syncthreads();

        // Publish tables; reuse s_cnt as placement cursor.
        for (int i = tid; i < nbuckets; i += 256) {
            subcnt[(size_t)i * NCHUNK + chunk] = s_cnt[i];
            suboff[(size_t)i * NCHUNK + chunk] = s_off[i];
            s_cnt[i] = 0;
        }
        __syncthreads();

        const size_t base = (size_t)chunk * epc;
        for (int e = e0 + tid; e < e1; e += 256) {
            const int t  = tidx[e];
            const int b  = t >> BSHIFT;
            const int tl = t & (BNODES - 1);
            const unsigned meta = (unsigned)sidx[e] | ((unsigned)tl << 17);
            const float w = esgn[e] * enorm[e];
            const int slot = atomicAdd(&s_cnt[b], 1);
            records[base + s_off[b] + slot] =
                (unsigned long long)meta |
                ((unsigned long long)__builtin_bit_cast(unsigned, w) << 32);
        }
    } else {
        const int c = ((int)blockIdx.x - NCHUNK) * (int)blockDim.x + (int)threadIdx.x;
        if (c < n_cvt8) {
            const f32x4 a = __builtin_nontemporal_load(
                reinterpret_cast<const f32x4*>(input + (size_t)c * 8));
            const f32x4 b = __builtin_nontemporal_load(
                reinterpret_cast<const f32x4*>(input + (size_t)c * 8 + 4));
            uint4 p;
            p.x = bf16rne(a.x) | (bf16rne(a.y) << 16);
            p.y = bf16rne(a.z) | (bf16rne(a.w) << 16);
            p.z = bf16rne(b.x) | (bf16rne(b.y) << 16);
            p.w = bf16rne(b.z) | (bf16rne(b.w) << 16);
            *reinterpret_cast<uint4*>(input_bf + (size_t)c * 4) = p;
        }
    }
}

// B: one block (256 thr = 4 waves) per bucket of 64 nodes.
// The last block to finish also drains the ovf list (exact fp32 fixup).
__global__ __launch_bounds__(256)
void bucket_gather(const int* __restrict__ subcnt,
                   const int* __restrict__ suboff,
                   const unsigned long long* __restrict__ records,
                   const unsigned* __restrict__ input_bf,
                   const float* __restrict__ input,
                   float* __restrict__ out,
                   Ovf* __restrict__ ovf,
                   int* __restrict__ ovf_count,   // [0]=ovf, [1]=done
                   int ovf_cap,
                   int n_nodes, int epc) {
    __shared__ int      s_segoff[NCHUNK];
    __shared__ int      s_pref[NCHUNK + 1];
    __shared__ int      s_wtot[4];
    __shared__ int      s_ncnt[BNODES];
    __shared__ unsigned s_rec[BNODES][NCAP];   // src<<15 | w*2^15
    __shared__ int      s_islast;

    const int b    = blockIdx.x;
    const int tid  = threadIdx.x;
    const int lane = tid & 63;
    const int wv   = tid >> 6;

    if (tid < BNODES) { s_ncnt[tid] = 0; s_rec[tid][0] = 0u; }
    s_segoff[tid] = suboff[(size_t)b * NCHUNK + tid];

    // Per-wave shfl scan of 64 counts each + wave-total combine (2 barriers).
    const int mycnt = subcnt[(size_t)b * NCHUNK + tid];
    int v = mycnt;
    #pragma unroll
    for (int d = 1; d < 64; d <<= 1) {
        const int u = __shfl_up(v, d);
        if (lane >= d) v += u;
    }
    if (lane == 63) s_wtot[wv] = v;
    __syncthreads();
    int wbase = 0;
    #pragma unroll
    for (int k = 0; k < 3; ++k) wbase += (k < wv) ? s_wtot[k] : 0;
    s_pref[tid + 1] = v + wbase;
    if (tid == 0) s_pref[0] = 0;
    __syncthreads();

    // Flattened push: every thread drains record i of this bucket.
    const int total = s_pref[NCHUNK];
    for (int i = tid; i < total; i += 256) {
        int lo = 0, hi = NCHUNK - 1;
        while (lo < hi) {
            const int mid = (lo + hi + 1) >> 1;
            if (s_pref[mid] <= i) lo = mid; else hi = mid - 1;
        }
        const unsigned long long rec =
            records[(size_t)lo * epc + s_segoff[lo] + (i - s_pref[lo])];
        const unsigned meta = (unsigned)rec;
        const int   src = (int)(meta & 0x1FFFFu);
        const int   tl  = (int)(meta >> 17) & (BNODES - 1);
        const float w   = __builtin_bit_cast(float, (unsigned)(rec >> 32));
        const int slot = atomicAdd(&s_ncnt[tl], 1);
        const bool ok  = (w >= 0.f) && (w < 1.f);
        if (slot < NCAP) {
            unsigned word = 0u;
            if (ok) {
                unsigned wq = (unsigned)(w * 32768.f + 0.5f);
                if (wq > 32767u) wq = 32767u;
                word = ((unsigned)src << 15) | wq;
            }
            s_rec[tl][slot] = word;
            if (!ok) push_ovf(ovf, ovf_count, ovf_cap, b * BNODES + tl, src, w);
        } else {
            push_ovf(ovf, ovf_count, ovf_cap, b * BNODES + tl, src, w);
        }
    }
    __syncthreads();

    // Gather: wave wv owns pairs (base, base+4), base = wv, wv+8, ...
    for (int base = wv; base < BNODES; base += 8) {
        const int nlA = base;
        const int nlB = base + 4;
        const int nodeA = b * BNODES + nlA;
        const int nodeB = b * BNODES + nlB;
        const int cntA = (nodeA < n_nodes) ? min(s_ncnt[nlA], NCAP) : 0;
        const int cntB = (nodeB < n_nodes) ? min(s_ncnt[nlB], NCAP) : 0;
        const int cmax = max(cntA, cntB);

        float2 a0 = make_float2(0.f, 0.f), a1 = make_float2(0.f, 0.f);
        float2 b0 = make_float2(0.f, 0.f), b1 = make_float2(0.f, 0.f);

        for (int j = 0; j < cmax; j += 4) {
            if (j < cntA) {
                unsigned rc[4], vv[4];
                float    wq[4];
                #pragma unroll
                for (int k = 0; k < 4; ++k) {
                    const int jk = min(j + k, cntA - 1);
                    rc[k] = s_rec[nlA][jk];
                    wq[k] = (j + k < cntA)
                          ? (float)(rc[k] & 0x7FFFu) * (1.f / 32768.f) : 0.f;
                }
                #pragma unroll
                for (int k = 0; k < 4; ++k)
                    vv[k] = input_bf[(size_t)(rc[k] >> 15) * 64 + lane];
                #pragma unroll
                for (int k = 0; k < 4; k += 2) {
                    a0.x += __builtin_bit_cast(float, vv[k] << 16) * wq[k];
                    a0.y += __builtin_bit_cast(float, vv[k] & 0xFFFF0000u) * wq[k];
                    a1.x += __builtin_bit_cast(float, vv[k+1] << 16) * wq[k+1];
                    a1.y += __builtin_bit_cast(float, vv[k+1] & 0xFFFF0000u) * wq[k+1];
                }
            }
            if (j < cntB) {
                unsigned rc[4], vv[4];
                float    wq[4];
                #pragma unroll
                for (int k = 0; k < 4; ++k) {
                    const int jk = min(j + k, cntB - 1);
                    rc[k] = s_rec[nlB][jk];
                    wq[k] = (j + k < cntB)
                          ? (float)(rc[k] & 0x7FFFu) * (1.f / 32768.f) : 0.f;
                }
                #pragma unroll
                for (int k = 0; k < 4; ++k)
                    vv[k] = input_bf[(size_t)(rc[k] >> 15) * 64 + lane];
                #pragma unroll
                for (int k = 0; k < 4; k += 2) {
                    b0.x += __builtin_bit_cast(float, vv[k] << 16) * wq[k];
                    b0.y += __builtin_bit_cast(float, vv[k] & 0xFFFF0000u) * wq[k];
                    b1.x += __builtin_bit_cast(float, vv[k+1] << 16) * wq[k+1];
                    b1.y += __builtin_bit_cast(float, vv[k+1] & 0xFFFF0000u) * wq[k+1];
                }
            }
        }

        if (nodeA < n_nodes) {
            f32x2 r; r.x = a0.x + a1.x; r.y = a0.y + a1.y;
            __builtin_nontemporal_store(r,
                reinterpret_cast<f32x2*>(out + (size_t)nodeA * 128 + lane * 2));
        }
        if (nodeB < n_nodes) {
            f32x2 r; r.x = b0.x + b1.x; r.y = b0.y + b1.y;
            __builtin_nontemporal_store(r,
                reinterpret_cast<f32x2*>(out + (size_t)nodeB * 128 + lane * 2));
        }
    }

    // Last-block fixup: drain ovf (exact fp32) after ALL blocks' stores.
    __threadfence();
    __syncthreads();
    if (tid == 0) {
        const int done = atomicAdd(&ovf_count[1], 1);
        s_islast = (done == (int)gridDim.x - 1);
    }
    __syncthreads();
    if (s_islast) {
        const int n = min(ovf_count[0], ovf_cap);
        for (int i = wv; i < n; i += 4) {
            const Ovf o = ovf[i];
            const float2 vv = *reinterpret_cast<const float2*>(
                input + (size_t)o.src * 128 + lane * 2);
            float* dst = out + (size_t)o.t * 128 + lane * 2;
            atomicAdd(dst + 0, vv.x * o.w);
            atomicAdd(dst + 1, vv.y * o.w);
        }
    }
}

// Fallback (round-1 atomic scatter) for unexpected shapes / tiny ws.
__global__ void graphconv_scatter(const float* __restrict__ input,
                                  const int* __restrict__ sidx,
                                  const int* __restrict__ tidx,
                                  const float* __restrict__ enorm,
                                  const float* __restrict__ esgn,
                                  float* __restrict__ out,
                                  int n_edges) {
    const int gtid   = blockIdx.x * blockDim.x + threadIdx.x;
    const int wave   = gtid >> 6;
    const int lane   = threadIdx.x & 63;
    const int nwaves = (gridDim.x * blockDim.x) >> 6;
    for (int e = wave; e < n_edges; e += nwaves) {
        const float w = esgn[e] * enorm[e];
        const float2 v = *reinterpret_cast<const float2*>(input + (size_t)(sidx[e] * 128 + lane * 2));
        float* dst = out + (size_t)(tidx[e] * 128 + lane * 2);
        atomicAdd(dst + 0, v.x * w);
        atomicAdd(dst + 1, v.y * w);
    }
}

extern "C" void kernel_launch(void* const* d_in, const int* in_sizes, int n_in,
                              void* d_out, int out_size, void* d_ws, size_t ws_size,
                              hipStream_t stream) {
    const float* input = (const float*)d_in[0];
    const int*   sidx  = (const int*)d_in[1];
    const int*   tidx  = (const int*)d_in[2];
    const float* enorm = (const float*)d_in[3];
    const float* esgn  = (const float*)d_in[4];
    float*       out   = (float*)d_out;

    const int n_edges  = in_sizes[1];
    const int n_nodes  = in_sizes[0] / 128;
    const int n_elem   = in_sizes[0];
    const int nbuckets = (n_nodes + BNODES - 1) >> BSHIFT;
    const int epc      = (n_edges + NCHUNK - 1) / NCHUNK;

    // ws layout: [subcnt nb*NCHUNK][suboff nb*NCHUNK][ovf+done 2 ints][pad256]
    //            [records][shadow][ovf]
    const size_t tbl_ints  = (size_t)nbuckets * NCHUNK;
    const size_t hdr_bytes = (2 * tbl_ints + 2) * sizeof(int);
    const size_t rec_off   = (hdr_bytes + 255) & ~(size_t)255;
    const size_t rec_bytes = (size_t)NCHUNK * epc * sizeof(unsigned long long);
    const size_t bf_off    = rec_off + rec_bytes;
    const size_t bf_bytes  = (size_t)n_elem * 2;
    const size_t ovf_off   = bf_off + bf_bytes;
    const size_t min_ovf   = 4096 * sizeof(Ovf);

    if (nbuckets > MAXB || n_nodes > (1 << 17) || ws_size < ovf_off + min_ovf) {
        (void)hipMemsetAsync(d_out, 0, (size_t)out_size * sizeof(float), stream);
        int grid = (n_edges * 64 + 255) / 256;
        if (grid > 2048) grid = 2048;
        graphconv_scatter<<<grid, 256, 0, stream>>>(input, sidx, tidx, enorm, esgn,
                                                    out, n_edges);
        return;
    }

    int*      subcnt    = (int*)d_ws;
    int*      suboff    = subcnt + tbl_ints;
    int*      ovf_count = suboff + tbl_ints;        // [0]=ovf, [1]=done
    unsigned long long* records = (unsigned long long*)((char*)d_ws + rec_off);
    unsigned* input_bf  = (unsigned*)((char*)d_ws + bf_off);
    Ovf*      ovf       = (Ovf*)((char*)d_ws + ovf_off);
    int       ovf_cap   = (int)((ws_size - ovf_off) / sizeof(Ovf));
    if (ovf_cap > n_edges) ovf_cap = n_edges;

    const int block = 256;
    const int n_cvt8 = n_elem / 8;
    const int cvt_blocks = (n_cvt8 + block - 1) / block;

    build_convert<<<NCHUNK + cvt_blocks, block, 0, stream>>>(
        tidx, sidx, enorm, esgn, subcnt, suboff, records, ovf_count,
        n_edges, nbuckets, epc, input, input_bf, n_cvt8);

    bucket_gather<<<nbuckets, block, 0, stream>>>(
        subcnt, suboff, records, input_bf, input, out, ovf, ovf_count, ovf_cap,
        n_nodes, epc);
}

// Round 18
// 67.137 us; speedup vs baseline: 3.2411x; 3.2411x over previous
//
#include <hip/hip_runtime.h>
#include <hip/hip_bf16.h>

// GraphConv: out[t] = sum_{e: tidx[e]==t} input[sidx[e]] * (esgn[e]*enorm[e])
// N_NODES=100000, N_FEAT=128, N_EDGES=600000, fp32.
//
// Round 18 = round 16 (67.7us, best) + per-wave shfl scan only.
// Round 17's last-block-fixup fold regressed 3x: __threadfence() per block
// (1563x) drains all outstanding stores + cache sync -> gather 41->194us.
// NEVER put device-scope fences in a throughput kernel's epilogue here.
// Separate fixup_ovf dispatch restored (grid 8; drains ~0 items).

#define NCHUNK 256
#define BSHIFT 6
#define BNODES 64
#define NCAP   24
#define MAXB   2048

typedef float f32x2 __attribute__((ext_vector_type(2)));
typedef float f32x4 __attribute__((ext_vector_type(4)));

struct Ovf { int t; int src; float w; };

__device__ __forceinline__ unsigned bf16rne(float f) {
    unsigned u = __builtin_bit_cast(unsigned, f);
    return (u + 0x7FFFu + ((u >> 16) & 1u)) >> 16;
}

__device__ __forceinline__ void push_ovf(Ovf* ovf, int* ovf_count, int ovf_cap,
                                         int t, int s, float w) {
    const int o = atomicAdd(ovf_count, 1);
    if (o < ovf_cap) { Ovf v; v.t = t; v.src = s; v.w = w; ovf[o] = v; }
}

// A: blocks [0,NCHUNK): per-chunk hist -> scan -> place (exact CSR, dense
//    8B record writes). blocks [NCHUNK,..): fp32 -> bf16 shadow convert.
__global__ __launch_bounds__(256)
void build_convert(const int* __restrict__ tidx,
                   const int* __restrict__ sidx,
                   const float* __restrict__ enorm,
                   const float* __restrict__ esgn,
                   int* __restrict__ subcnt,     // [nb][NCHUNK]
                   int* __restrict__ suboff,     // [nb][NCHUNK]
                   unsigned long long* __restrict__ records,
                   int* __restrict__ ovf_count,
                   int n_edges, int nbuckets, int epc,
                   const float* __restrict__ input,
                   unsigned* __restrict__ input_bf,
                   int n_cvt8) {
    if ((int)blockIdx.x < NCHUNK) {
        __shared__ int s_cnt[MAXB];
        __shared__ int s_off[MAXB];
        __shared__ int s_part[256];
        const int chunk = blockIdx.x;
        const int tid   = threadIdx.x;

        if (chunk == 0 && tid == 0) *ovf_count = 0;   // only gather pushes ovf

        for (int i = tid; i < nbuckets; i += 256) s_cnt[i] = 0;
        __syncthreads();

        const int e0 = chunk * epc;
        const int e1 = min(e0 + epc, n_edges);
        for (int e = e0 + tid; e < e1; e += 256)
            atomicAdd(&s_cnt[tidx[e] >> BSHIFT], 1);
        __syncthreads();

        // Exclusive scan over nbuckets (<=MAXB): 8/thread + partials scan.
        int local[8];
        int sum = 0;
        #pragma unroll
        for (int k = 0; k < 8; ++k) {
            const int idx = tid * 8 + k;
            local[k] = (idx < nbuckets) ? s_cnt[idx] : 0;
            sum += local[k];
        }
        s_part[tid] = sum;
        __syncthreads();
        for (int d = 1; d < 256; d <<= 1) {
            const int v = (tid >= d) ? s_part[tid - d] : 0;
            __syncthreads();
            s_part[tid] += v;
            __syncthreads();
        }
        int run = s_part[tid] - sum;
        #pragma unroll
        for (int k = 0; k < 8; ++k) {
            const int idx = tid * 8 + k;
            if (idx < nbuckets) { s_off[idx] = run; run += local[k]; }
        }
        __syncthreads();

        // Publish tables; reuse s_cnt as placement cursor.
        for (int i = tid; i < nbuckets; i += 256) {
            subcnt[(size_t)i * NCHUNK + chunk] = s_cnt[i];
            suboff[(size_t)i * NCHUNK + chunk] = s_off[i];
            s_cnt[i] = 0;
        }
        __syncthreads();

        const size_t base = (size_t)chunk * epc;
        for (int e = e0 + tid; e < e1; e += 256) {
            const int t  = tidx[e];
            const int b  = t >> BSHIFT;
            const int tl = t & (BNODES - 1);
            const unsigned meta = (unsigned)sidx[e] | ((unsigned)tl << 17);
            const float w = esgn[e] * enorm[e];
            const int slot = atomicAdd(&s_cnt[b], 1);
            records[base + s_off[b] + slot] =
                (unsigned long long)meta |
                ((unsigned long long)__builtin_bit_cast(unsigned, w) << 32);
        }
    } else {
        const int c = ((int)blockIdx.x - NCHUNK) * (int)blockDim.x + (int)threadIdx.x;
        if (c < n_cvt8) {
            const f32x4 a = __builtin_nontemporal_load(
                reinterpret_cast<const f32x4*>(input + (size_t)c * 8));
            const f32x4 b = __builtin_nontemporal_load(
                reinterpret_cast<const f32x4*>(input + (size_t)c * 8 + 4));
            uint4 p;
            p.x = bf16rne(a.x) | (bf16rne(a.y) << 16);
            p.y = bf16rne(a.z) | (bf16rne(a.w) << 16);
            p.z = bf16rne(b.x) | (bf16rne(b.y) << 16);
            p.w = bf16rne(b.z) | (bf16rne(b.w) << 16);
            *reinterpret_cast<uint4*>(input_bf + (size_t)c * 4) = p;
        }
    }
}

// B: one block (256 thr = 4 waves) per bucket of 64 nodes.
__global__ __launch_bounds__(256)
void bucket_gather(const int* __restrict__ subcnt,
                   const int* __restrict__ suboff,
                   const unsigned long long* __restrict__ records,
                   const unsigned* __restrict__ input_bf,
                   float* __restrict__ out,
                   Ovf* __restrict__ ovf,
                   int* __restrict__ ovf_count,
                   int ovf_cap,
                   int n_nodes, int epc) {
    __shared__ int      s_segoff[NCHUNK];
    __shared__ int      s_pref[NCHUNK + 1];
    __shared__ int      s_wtot[4];
    __shared__ int      s_ncnt[BNODES];
    __shared__ unsigned s_rec[BNODES][NCAP];   // src<<15 | w*2^15

    const int b    = blockIdx.x;
    const int tid  = threadIdx.x;
    const int lane = tid & 63;
    const int wv   = tid >> 6;

    if (tid < BNODES) { s_ncnt[tid] = 0; s_rec[tid][0] = 0u; }
    s_segoff[tid] = suboff[(size_t)b * NCHUNK + tid];

    // Per-wave shfl scan of 64 counts + wave-total combine (2 barriers).
    int v = subcnt[(size_t)b * NCHUNK + tid];
    #pragma unroll
    for (int d = 1; d < 64; d <<= 1) {
        const int u = __shfl_up(v, d);
        if (lane >= d) v += u;
    }
    if (lane == 63) s_wtot[wv] = v;
    __syncthreads();
    int wbase = 0;
    #pragma unroll
    for (int k = 0; k < 3; ++k) wbase += (k < wv) ? s_wtot[k] : 0;
    s_pref[tid + 1] = v + wbase;
    if (tid == 0) s_pref[0] = 0;
    __syncthreads();

    // Flattened push: every thread drains record i of this bucket.
    const int total = s_pref[NCHUNK];
    for (int i = tid; i < total; i += 256) {
        int lo = 0, hi = NCHUNK - 1;
        while (lo < hi) {
            const int mid = (lo + hi + 1) >> 1;
            if (s_pref[mid] <= i) lo = mid; else hi = mid - 1;
        }
        const unsigned long long rec =
            records[(size_t)lo * epc + s_segoff[lo] + (i - s_pref[lo])];
        const unsigned meta = (unsigned)rec;
        const int   src = (int)(meta & 0x1FFFFu);
        const int   tl  = (int)(meta >> 17) & (BNODES - 1);
        const float w   = __builtin_bit_cast(float, (unsigned)(rec >> 32));
        const int slot = atomicAdd(&s_ncnt[tl], 1);
        const bool ok  = (w >= 0.f) && (w < 1.f);
        if (slot < NCAP) {
            unsigned word = 0u;
            if (ok) {
                unsigned wq = (unsigned)(w * 32768.f + 0.5f);
                if (wq > 32767u) wq = 32767u;
                word = ((unsigned)src << 15) | wq;
            }
            s_rec[tl][slot] = word;
            if (!ok) push_ovf(ovf, ovf_count, ovf_cap, b * BNODES + tl, src, w);
        } else {
            push_ovf(ovf, ovf_count, ovf_cap, b * BNODES + tl, src, w);
        }
    }
    __syncthreads();

    // Gather: wave wv owns pairs (base, base+4), base = wv, wv+8, ...
    for (int base = wv; base < BNODES; base += 8) {
        const int nlA = base;
        const int nlB = base + 4;
        const int nodeA = b * BNODES + nlA;
        const int nodeB = b * BNODES + nlB;
        const int cntA = (nodeA < n_nodes) ? min(s_ncnt[nlA], NCAP) : 0;
        const int cntB = (nodeB < n_nodes) ? min(s_ncnt[nlB], NCAP) : 0;
        const int cmax = max(cntA, cntB);

        float2 a0 = make_float2(0.f, 0.f), a1 = make_float2(0.f, 0.f);
        float2 b0 = make_float2(0.f, 0.f), b1 = make_float2(0.f, 0.f);

        for (int j = 0; j < cmax; j += 4) {
            if (j < cntA) {
                unsigned rc[4], vv[4];
                float    wq[4];
                #pragma unroll
                for (int k = 0; k < 4; ++k) {
                    const int jk = min(j + k, cntA - 1);
                    rc[k] = s_rec[nlA][jk];
                    wq[k] = (j + k < cntA)
                          ? (float)(rc[k] & 0x7FFFu) * (1.f / 32768.f) : 0.f;
                }
                #pragma unroll
                for (int k = 0; k < 4; ++k)
                    vv[k] = input_bf[(size_t)(rc[k] >> 15) * 64 + lane];
                #pragma unroll
                for (int k = 0; k < 4; k += 2) {
                    a0.x += __builtin_bit_cast(float, vv[k] << 16) * wq[k];
                    a0.y += __builtin_bit_cast(float, vv[k] & 0xFFFF0000u) * wq[k];
                    a1.x += __builtin_bit_cast(float, vv[k+1] << 16) * wq[k+1];
                    a1.y += __builtin_bit_cast(float, vv[k+1] & 0xFFFF0000u) * wq[k+1];
                }
            }
            if (j < cntB) {
                unsigned rc[4], vv[4];
                float    wq[4];
                #pragma unroll
                for (int k = 0; k < 4; ++k) {
                    const int jk = min(j + k, cntB - 1);
                    rc[k] = s_rec[nlB][jk];
                    wq[k] = (j + k < cntB)
                          ? (float)(rc[k] & 0x7FFFu) * (1.f / 32768.f) : 0.f;
                }
                #pragma unroll
                for (int k = 0; k < 4; ++k)
                    vv[k] = input_bf[(size_t)(rc[k] >> 15) * 64 + lane];
                #pragma unroll
                for (int k = 0; k < 4; k += 2) {
                    b0.x += __builtin_bit_cast(float, vv[k] << 16) * wq[k];
                    b0.y += __builtin_bit_cast(float, vv[k] & 0xFFFF0000u) * wq[k];
                    b1.x += __builtin_bit_cast(float, vv[k+1] << 16) * wq[k+1];
                    b1.y += __builtin_bit_cast(float, vv[k+1] & 0xFFFF0000u) * wq[k+1];
                }
            }
        }

        if (nodeA < n_nodes) {
            f32x2 r; r.x = a0.x + a1.x; r.y = a0.y + a1.y;
            __builtin_nontemporal_store(r,
                reinterpret_cast<f32x2*>(out + (size_t)nodeA * 128 + lane * 2));
        }
        if (nodeB < n_nodes) {
            f32x2 r; r.x = b0.x + b1.x; r.y = b0.y + b1.y;
            __builtin_nontemporal_store(r,
                reinterpret_cast<f32x2*>(out + (size_t)nodeB * 128 + lane * 2));
        }
    }
}

__global__ void fixup_ovf(const float* __restrict__ input,
                          const Ovf* __restrict__ ovf,
                          const int* __restrict__ ovf_count,
                          float* __restrict__ out,
                          int ovf_cap) {
    const int n = min(*ovf_count, ovf_cap);
    const int wave   = (blockIdx.x * blockDim.x + threadIdx.x) >> 6;
    const int lane   = threadIdx.x & 63;
    const int nwaves = (gridDim.x * blockDim.x) >> 6;
    for (int i = wave; i < n; i += nwaves) {
        const Ovf o = ovf[i];
        const float2 v = *reinterpret_cast<const float2*>(input + (size_t)(o.src * 128 + lane * 2));
        float* dst = out + (size_t)(o.t * 128 + lane * 2);
        atomicAdd(dst + 0, v.x * o.w);
        atomicAdd(dst + 1, v.y * o.w);
    }
}

// Fallback (round-1 atomic scatter) for unexpected shapes / tiny ws.
__global__ void graphconv_scatter(const float* __restrict__ input,
                                  const int* __restrict__ sidx,
                                  const int* __restrict__ tidx,
                                  const float* __restrict__ enorm,
                                  const float* __restrict__ esgn,
                                  float* __restrict__ out,
                                  int n_edges) {
    const int gtid   = blockIdx.x * blockDim.x + threadIdx.x;
    const int wave   = gtid >> 6;
    const int lane   = threadIdx.x & 63;
    const int nwaves = (gridDim.x * blockDim.x) >> 6;
    for (int e = wave; e < n_edges; e += nwaves) {
        const float w = esgn[e] * enorm[e];
        const float2 v = *reinterpret_cast<const float2*>(input + (size_t)(sidx[e] * 128 + lane * 2));
        float* dst = out + (size_t)(tidx[e] * 128 + lane * 2);
        atomicAdd(dst + 0, v.x * w);
        atomicAdd(dst + 1, v.y * w);
    }
}

extern "C" void kernel_launch(void* const* d_in, const int* in_sizes, int n_in,
                              void* d_out, int out_size, void* d_ws, size_t ws_size,
                              hipStream_t stream) {
    const float* input = (const float*)d_in[0];
    const int*   sidx  = (const int*)d_in[1];
    const int*   tidx  = (const int*)d_in[2];
    const float* enorm = (const float*)d_in[3];
    const float* esgn  = (const float*)d_in[4];
    float*       out   = (float*)d_out;

    const int n_edges  = in_sizes[1];
    const int n_nodes  = in_sizes[0] / 128;
    const int n_elem   = in_sizes[0];
    const int nbuckets = (n_nodes + BNODES - 1) >> BSHIFT;
    const int epc      = (n_edges + NCHUNK - 1) / NCHUNK;

    // ws layout: [subcnt nb*NCHUNK][suboff nb*NCHUNK][ovf_count][pad256]
    //            [records][shadow][ovf]
    const size_t tbl_ints  = (size_t)nbuckets * NCHUNK;
    const size_t hdr_bytes = (2 * tbl_ints + 1) * sizeof(int);
    const size_t rec_off   = (hdr_bytes + 255) & ~(size_t)255;
    const size_t rec_bytes = (size_t)NCHUNK * epc * sizeof(unsigned long long);
    const size_t bf_off    = rec_off + rec_bytes;
    const size_t bf_bytes  = (size_t)n_elem * 2;
    const size_t ovf_off   = bf_off + bf_bytes;
    const size_t min_ovf   = 4096 * sizeof(Ovf);

    if (nbuckets > MAXB || n_nodes > (1 << 17) || ws_size < ovf_off + min_ovf) {
        (void)hipMemsetAsync(d_out, 0, (size_t)out_size * sizeof(float), stream);
        int grid = (n_edges * 64 + 255) / 256;
        if (grid > 2048) grid = 2048;
        graphconv_scatter<<<grid, 256, 0, stream>>>(input, sidx, tidx, enorm, esgn,
                                                    out, n_edges);
        return;
    }

    int*      subcnt    = (int*)d_ws;
    int*      suboff    = subcnt + tbl_ints;
    int*      ovf_count = suboff + tbl_ints;
    unsigned long long* records = (unsigned long long*)((char*)d_ws + rec_off);
    unsigned* input_bf  = (unsigned*)((char*)d_ws + bf_off);
    Ovf*      ovf       = (Ovf*)((char*)d_ws + ovf_off);
    int       ovf_cap   = (int)((ws_size - ovf_off) / sizeof(Ovf));
    if (ovf_cap > n_edges) ovf_cap = n_edges;

    const int block = 256;
    const int n_cvt8 = n_elem / 8;
    const int cvt_blocks = (n_cvt8 + block - 1) / block;

    build_convert<<<NCHUNK + cvt_blocks, block, 0, stream>>>(
        tidx, sidx, enorm, esgn, subcnt, suboff, records, ovf_count,
        n_edges, nbuckets, epc, input, input_bf, n_cvt8);

    bucket_gather<<<nbuckets, block, 0, stream>>>(
        subcnt, suboff, records, input_bf, out, ovf, ovf_count, ovf_cap,
        n_nodes, epc);

    fixup_ovf<<<8, block, 0, stream>>>(input, ovf, ovf_count, out, ovf_cap);
}